// Round 8
// baseline (192.063 us; speedup 1.0000x reference)
//
#include <hip/hip_runtime.h>
#include <stdint.h>

#define M_DIM 4096
#define I_DIM 1024
#define O_DIM 1024
#define KB 6
#define K_DIM (I_DIM * KB)   // 6144
#define SPLITS 4

typedef __attribute__((ext_vector_type(8))) short short8;
typedef __attribute__((ext_vector_type(4))) float f32x4;
typedef __attribute__((ext_vector_type(4))) unsigned int u32x4;
typedef __attribute__((ext_vector_type(4))) float hfloat4;
typedef __attribute__((ext_vector_type(8))) _Float16 h16x8;

__device__ __forceinline__ unsigned short f2bf(float f) {
  union { float f; unsigned int u; } v; v.f = f;
  unsigned int u = v.u;
  unsigned int r = (u + 0x7FFFu + ((u >> 16) & 1u)) >> 16;
  return (unsigned short)r;
}

// ---- Kernel 1 (fat): blocks [0,2048): basis planes -> bf16 A[4096][6144]
//                      blocks [2048,3072): coeffs -> bf16 Bt[1024][6144] + bias partials
__global__ __launch_bounds__(256) void k_prep(const float* __restrict__ x,
                                              const float* __restrict__ C,
                                              unsigned short* __restrict__ A,
                                              unsigned short* __restrict__ Bt,
                                              float* __restrict__ partB) {
  const int bid = blockIdx.x;
  if (bid < 2048) {
    int t = bid * 256 + threadIdx.x;
    long e0 = (long)t * 8;
    const hfloat4* xp = (const hfloat4*)(x + e0);
    hfloat4 v0 = xp[0], v1 = xp[1];
    float xv[8];
    xv[0]=v0[0]; xv[1]=v0[1]; xv[2]=v0[2]; xv[3]=v0[3];
    xv[4]=v1[0]; xv[5]=v1[1]; xv[6]=v1[2]; xv[7]=v1[3];
    unsigned short outv[48];
#pragma unroll
    for (int e = 0; e < 8; ++e) {
      float s  = 1.0f / (1.0f + __expf(-xv[e]));
      float b2 = s, b3 = s, b4 = s * s;
      float b5 = fmaf(s, b4, b3 + b2 + 1.0f);
      float b6 = fmaf(s, b5, b4 + b3 + b2 + 1.0f);
      float b7 = fmaf(s, b6, b5 + b4 + b3 + b2);
      float b8 = fmaf(s, b7, b6 + b5 + b4 + b3);
      outv[e*6+0] = f2bf(s);
      outv[e*6+1] = f2bf(b4);
      outv[e*6+2] = f2bf(b5);
      outv[e*6+3] = f2bf(b6);
      outv[e*6+4] = f2bf(b7);
      outv[e*6+5] = f2bf(b8);
    }
    u32x4* dst = (u32x4*)(A + e0 * KB);
    const u32x4* srcv = (const u32x4*)outv;
#pragma unroll
    for (int q = 0; q < 6; ++q) dst[q] = srcv[q];
  } else {
    __shared__ unsigned short tile[32 * 192];
    __shared__ float bred[256];
    int b = bid - 2048;
    int i0 = (b & 31) * 32, o0 = (b >> 5) * 32;
    int t = threadIdx.x;
    int ol = t & 31, ig = t >> 5;
    float bsum = 0.f;
#pragma unroll
    for (int r = 0; r < 4; ++r) {
      int il = ig + r * 8;
      const float* p = C + (size_t)(i0 + il) * (O_DIM * 9) + (size_t)(o0 + ol) * 9;
      float c1 = p[1];
      float c2 = p[2], c3 = p[3], c4 = p[4], c5 = p[5], c6 = p[6], c7 = p[7], c8 = p[8];
      bsum += c1;
      unsigned short* q = &tile[ol * 192 + il * 6];
      q[0] = f2bf(c2 + c3);
      q[1] = f2bf(c4);
      q[2] = f2bf(c5);
      q[3] = f2bf(c6);
      q[4] = f2bf(c7);
      q[5] = f2bf(c8);
    }
    bred[t] = bsum;
    __syncthreads();
    if (t < 32) {
      float s = 0.f;
#pragma unroll
      for (int g = 0; g < 8; ++g) s += bred[g * 32 + t];
      partB[(size_t)(b & 31) * O_DIM + o0 + t] = s;
    }
    const u32x4* lsrc = (const u32x4*)tile;
#pragma unroll
    for (int r = 0; r < 3; ++r) {
      int c = t + r * 256;
      int row = c / 24, off = c % 24;
      u32x4* gdst = (u32x4*)(Bt + (size_t)(o0 + row) * K_DIM + (size_t)i0 * 6 + off * 8);
      *gdst = lsrc[c];
    }
  }
}

// ------- Kernel 2b: final bias reduce (32 partials) + zero fixup counters ----
__global__ __launch_bounds__(256) void k_bias2(const float* __restrict__ partB,
                                               float* __restrict__ bias,
                                               unsigned int* __restrict__ cnt) {
  int o = blockIdx.x * 256 + threadIdx.x;     // 4 blocks
  if (blockIdx.x == 0 && threadIdx.x < 64) cnt[threadIdx.x] = 0;
  float s = 0.f;
#pragma unroll
  for (int ib = 0; ib < 32; ++ib) s += partB[(size_t)ib * O_DIM + o];
  bias[o] = s;
}

// ---------------- Kernel 3: 256x256 bf16 GEMM, read-ahead pipeline -----------
// 512 thr = 8 waves (2M x 4N); per-wave C = 128x64. BK=64, LDS dbuf 128KB.
// Per tile: stage(nb) + readK(f1) issue, then 64 MFMA (f0 already in regs from
// last iteration's post-barrier readK) covering all LDS reads + both drains.
// One barrier/tile. SPLIT: f16 partials + in-kernel counter-based fixup.
#define SBAR __builtin_amdgcn_sched_barrier(0)

template<bool SPLIT>
__global__ __launch_bounds__(512, 2) void k_gemm8(const unsigned short* __restrict__ A,
                                                  const unsigned short* __restrict__ B,
                                                  const float* __restrict__ bias,
                                                  _Float16* __restrict__ part,
                                                  float* __restrict__ out,
                                                  unsigned int* __restrict__ cnt) {
  constexpr int CK = SPLIT ? (K_DIM / SPLITS) : K_DIM;   // 1536 / 6144
  constexpr int NT = CK / 64;                            // 24 / 96
  constexpr int PPX = SPLIT ? 8 : 2;                     // (y,z) panels per XCD
  __shared__ char lds[131072];   // [2 buf][A 32KB | B 32KB]
  __shared__ unsigned int winner;
  const int tid = threadIdx.x;
  const int lane = tid & 63, wid = tid >> 6;
  const int wm = wid >> 2, wn = wid & 3;
  const int l15 = lane & 15, lk = lane >> 4, l7 = lane & 7;
  // XCD-grouped bijective remap: 4 n-blocks of one (ym,zk) panel -> same XCD
  const int flat = blockIdx.x + (blockIdx.y << 2) + (blockIdx.z << 6);
  const int xcd = flat & 7, slot = flat >> 3;
  const int panel = xcd * PPX + (slot >> 2);
  const int xn = slot & 3;
  const int ym = panel & 15, zk = panel >> 4;
  const int m0 = ym * 256, n0 = xn * 256;
  const size_t kb = (size_t)zk * CK;
  // staging: thread tid covers LDS rows tid>>3 (+64), chunk slot tid&7;
  // pre-swizzled global chunk = slot ^ (row&7)
  const int srow = tid >> 3;
  const int cg8 = (((tid & 7) ^ ((tid >> 3) & 7)) * 8);  // ushort offset
  // ds_read swizzled chunk offsets (row&7 == lane&7 for all frags)
  const int cx0 = (lk ^ l7) * 16;
  const int cx1 = ((4 + lk) ^ l7) * 16;
  const int arow = wm * 128 + l15;
  const int brow = wn * 64 + l15;

  auto gload = [&](const unsigned short* s, int ldsoff) {
    __builtin_amdgcn_global_load_lds((const __attribute__((address_space(1))) void*)s,
        (__attribute__((address_space(3))) void*)(lds + ldsoff), 16, 0, 0);
  };
  auto stageA = [&](int buf, int h, int kt2) {
    const unsigned short* s = A + (size_t)(m0 + h * 128 + srow) * K_DIM + kb + (size_t)kt2 * 64 + cg8;
    int d = buf * 65536 + h * 16384 + tid * 16;
    gload(s, d);
    gload(s + (size_t)64 * K_DIM, d + 8192);
  };
  auto stageB = [&](int buf, int h, int kt2) {
    const unsigned short* s = B + (size_t)(n0 + h * 128 + srow) * K_DIM + kb + (size_t)kt2 * 64 + cg8;
    int d = buf * 65536 + 32768 + h * 16384 + tid * 16;
    gload(s, d);
    gload(s + (size_t)64 * K_DIM, d + 8192);
  };

  // fragments: one K-half (12 x b128) per set
  short8 a0[8], b0v[4], a1[8], b1v[4];
  f32x4 acc[8][4];
#pragma unroll
  for (int i = 0; i < 8; ++i)
#pragma unroll
    for (int n = 0; n < 4; ++n)
#pragma unroll
      for (int j = 0; j < 4; ++j) acc[i][n][j] = 0.f;

  auto readK = [&](int buf, int cx, short8 (&av)[8], short8 (&bv)[4]) {
#pragma unroll
    for (int mi = 0; mi < 8; ++mi)
      av[mi] = *(const short8*)(lds + buf * 65536 + (arow + mi * 16) * 128 + cx);
#pragma unroll
    for (int ni = 0; ni < 4; ++ni)
      bv[ni] = *(const short8*)(lds + buf * 65536 + 32768 + (brow + ni * 16) * 128 + cx);
  };
  auto quadK = [&](short8 (&av)[8], short8 (&bv)[4]) {
#pragma unroll
    for (int mi = 0; mi < 8; ++mi)
#pragma unroll
      for (int ni = 0; ni < 4; ++ni)
        acc[mi][ni] = __builtin_amdgcn_mfma_f32_16x16x32_bf16(av[mi], bv[ni], acc[mi][ni], 0, 0, 0);
  };

  // prologue: stage tile0 into buf0, drain, barrier, read kc0 frags
  stageA(0, 0, 0); stageA(0, 1, 0); stageB(0, 0, 0); stageB(0, 1, 0);
  asm volatile("s_waitcnt vmcnt(0)" ::: "memory"); SBAR;
  __builtin_amdgcn_s_barrier(); SBAR;
  readK(0, cx0, a0, b0v);

#pragma unroll 1
  for (int kt = 0; kt < NT; ++kt) {
    const int buf = kt & 1, nb = buf ^ 1;
    // issue next tile's staging + current tile's kc1 reads, then 64 MFMAs.
    if (kt + 1 < NT) {
      stageA(nb, 0, kt + 1); stageA(nb, 1, kt + 1);
      stageB(nb, 0, kt + 1); stageB(nb, 1, kt + 1);
    }
    readK(buf, cx1, a1, b1v);
    __builtin_amdgcn_s_setprio(1);
    quadK(a0, b0v);          // f0 in regs since last iteration: no wait at entry
    quadK(a1, b1v);          // compiler inserts counted lgkmcnt for f1
    __builtin_amdgcn_s_setprio(0); SBAR;
    // drains fully covered by the 64-MFMA block above
    asm volatile("s_waitcnt lgkmcnt(0)" ::: "memory"); SBAR;   // WAR: f1 reads done
    if (kt + 1 < NT) {
      asm volatile("s_waitcnt vmcnt(0)" ::: "memory"); SBAR;   // RAW: staging done
      __builtin_amdgcn_s_barrier(); SBAR;
      readK(nb, cx0, a0, b0v);   // next tile kc0: overlaps next issue + quad(f0)
    }
  }

  // epilogue: C/D layout col = lane&15, row = (lane>>4)*4 + j
  if (SPLIT) {
    _Float16* base = part + (size_t)zk * ((size_t)M_DIM * O_DIM);
#pragma unroll
    for (int mi = 0; mi < 8; ++mi) {
      int r0 = m0 + wm * 128 + mi * 16 + (lk << 2);
#pragma unroll
      for (int ni = 0; ni < 4; ++ni) {
        int col = n0 + wn * 64 + ni * 16 + l15;
#pragma unroll
        for (int j = 0; j < 4; ++j)
          base[(size_t)(r0 + j) * O_DIM + col] = (_Float16)acc[mi][ni][j];
      }
    }
    // ---- split-K fixup: 4th block of this (x,y) tile reduces all planes ----
    __threadfence();                          // release partial stores
    if (tid == 0) {
      unsigned int old = __hip_atomic_fetch_add(&cnt[ym * 4 + xn], 1u,
                                                __ATOMIC_ACQ_REL, __HIP_MEMORY_SCOPE_AGENT);
      winner = (old == SPLITS - 1) ? 1u : 0u;
    }
    __syncthreads();
    if (winner) {
      __threadfence();                        // acquire side for all threads
      const size_t P = (size_t)M_DIM * O_DIM;
      int rg = tid >> 5, cc = tid & 31;
      int col = n0 + cc * 8;
      f32x4 bv0 = *(const f32x4*)(bias + col);
      f32x4 bv1 = *(const f32x4*)(bias + col + 4);
#pragma unroll
      for (int q = 0; q < 16; ++q) {
        size_t off = (size_t)(m0 + rg * 16 + q) * O_DIM + col;
        h16x8 p0 = *(const h16x8*)(part + off);
        h16x8 p1 = *(const h16x8*)(part + P + off);
        h16x8 p2 = *(const h16x8*)(part + 2 * P + off);
        h16x8 p3 = *(const h16x8*)(part + 3 * P + off);
        f32x4 r0, r1;
#pragma unroll
        for (int j = 0; j < 4; ++j) {
          r0[j] = (((float)p0[j] + (float)p1[j]) + ((float)p2[j] + (float)p3[j])) + bv0[j];
          r1[j] = (((float)p0[j+4] + (float)p1[j+4]) + ((float)p2[j+4] + (float)p3[j+4])) + bv1[j];
        }
        *(f32x4*)(out + off) = r0;
        *(f32x4*)(out + off + 4) = r1;
      }
    }
  } else {
#pragma unroll
    for (int mi = 0; mi < 8; ++mi) {
      int r0 = m0 + wm * 128 + mi * 16 + (lk << 2);
#pragma unroll
      for (int ni = 0; ni < 4; ++ni) {
        int col = n0 + wn * 64 + ni * 16 + l15;
        float bv = bias[col];
#pragma unroll
        for (int j = 0; j < 4; ++j)
          out[(size_t)(r0 + j) * O_DIM + col] = acc[mi][ni][j] + bv;
      }
    }
  }
}

extern "C" void kernel_launch(void* const* d_in, const int* in_sizes, int n_in,
                              void* d_out, int out_size, void* d_ws, size_t ws_size,
                              hipStream_t stream) {
  const float* x      = (const float*)d_in[0];
  const float* coeffs = (const float*)d_in[1];
  float* out = (float*)d_out;
  char* ws = (char*)d_ws;
  const size_t offA     = 0;
  const size_t offB     = 50331648;                // A: 4096*6144*2
  const size_t offBias  = offB + 12582912;         // Bt: 1024*6144*2
  const size_t offPartB = offBias + 4096;          // bias: 1024*4
  const size_t offPart  = offPartB + 131072;       // partB: 32*1024*4
  const size_t offCnt   = offPart + (size_t)SPLITS * M_DIM * O_DIM * 2;
  const size_t needSplit = offCnt + 256;

  unsigned short* A  = (unsigned short*)(ws + offA);
  unsigned short* Bt = (unsigned short*)(ws + offB);
  float* bias        = (float*)(ws + offBias);
  float* partB       = (float*)(ws + offPartB);
  _Float16* part     = (_Float16*)(ws + offPart);
  unsigned int* cnt  = (unsigned int*)(ws + offCnt);

  k_prep<<<3072, 256, 0, stream>>>(x, coeffs, A, Bt, partB);
  k_bias2<<<4, 256, 0, stream>>>(partB, bias, cnt);

  if (ws_size >= needSplit) {
    k_gemm8<true><<<dim3(O_DIM / 256, M_DIM / 256, SPLITS), 512, 0, stream>>>(A, Bt, bias, part, out, cnt);
  } else {
    k_gemm8<false><<<dim3(O_DIM / 256, M_DIM / 256, 1), 512, 0, stream>>>(A, Bt, bias, part, out, cnt);
  }
}

// Round 9
// 103.673 us; speedup vs baseline: 1.8526x; 1.8526x over previous
//
#include <hip/hip_runtime.h>
#include <stdint.h>

#define M_DIM 4096
#define I_DIM 1024
#define O_DIM 1024
#define KB 6
#define K_DIM (I_DIM * KB)   // 6144

typedef __attribute__((ext_vector_type(8))) short short8;
typedef __attribute__((ext_vector_type(4))) float f32x4;
typedef __attribute__((ext_vector_type(4))) unsigned int u32x4;
typedef __attribute__((ext_vector_type(4))) float hfloat4;
typedef __attribute__((ext_vector_type(8))) _Float16 h16x8;

__device__ __forceinline__ unsigned short f2bf(float f) {
  union { float f; unsigned int u; } v; v.f = f;
  unsigned int u = v.u;
  unsigned int r = (u + 0x7FFFu + ((u >> 16) & 1u)) >> 16;
  return (unsigned short)r;
}

// ---- Kernel 1 (fat): blocks [0,2048): basis planes -> bf16 A[4096][6144]
//                      blocks [2048,3072): coeffs -> bf16 Bt[1024][6144] + bias partials
__global__ __launch_bounds__(256) void k_prep(const float* __restrict__ x,
                                              const float* __restrict__ C,
                                              unsigned short* __restrict__ A,
                                              unsigned short* __restrict__ Bt,
                                              float* __restrict__ partB) {
  const int bid = blockIdx.x;
  if (bid < 2048) {
    int t = bid * 256 + threadIdx.x;
    long e0 = (long)t * 8;
    const hfloat4* xp = (const hfloat4*)(x + e0);
    hfloat4 v0 = xp[0], v1 = xp[1];
    float xv[8];
    xv[0]=v0[0]; xv[1]=v0[1]; xv[2]=v0[2]; xv[3]=v0[3];
    xv[4]=v1[0]; xv[5]=v1[1]; xv[6]=v1[2]; xv[7]=v1[3];
    unsigned short outv[48];
#pragma unroll
    for (int e = 0; e < 8; ++e) {
      float s  = 1.0f / (1.0f + __expf(-xv[e]));
      float b2 = s, b3 = s, b4 = s * s;
      float b5 = fmaf(s, b4, b3 + b2 + 1.0f);
      float b6 = fmaf(s, b5, b4 + b3 + b2 + 1.0f);
      float b7 = fmaf(s, b6, b5 + b4 + b3 + b2);
      float b8 = fmaf(s, b7, b6 + b5 + b4 + b3);
      outv[e*6+0] = f2bf(s);
      outv[e*6+1] = f2bf(b4);
      outv[e*6+2] = f2bf(b5);
      outv[e*6+3] = f2bf(b6);
      outv[e*6+4] = f2bf(b7);
      outv[e*6+5] = f2bf(b8);
    }
    u32x4* dst = (u32x4*)(A + e0 * KB);
    const u32x4* srcv = (const u32x4*)outv;
#pragma unroll
    for (int q = 0; q < 6; ++q) dst[q] = srcv[q];
  } else {
    __shared__ unsigned short tile[32 * 192];
    __shared__ float bred[256];
    int b = bid - 2048;
    int i0 = (b & 31) * 32, o0 = (b >> 5) * 32;
    int t = threadIdx.x;
    int ol = t & 31, ig = t >> 5;
    float bsum = 0.f;
#pragma unroll
    for (int r = 0; r < 4; ++r) {
      int il = ig + r * 8;
      const float* p = C + (size_t)(i0 + il) * (O_DIM * 9) + (size_t)(o0 + ol) * 9;
      float c1 = p[1];
      float c2 = p[2], c3 = p[3], c4 = p[4], c5 = p[5], c6 = p[6], c7 = p[7], c8 = p[8];
      bsum += c1;
      unsigned short* q = &tile[ol * 192 + il * 6];
      q[0] = f2bf(c2 + c3);
      q[1] = f2bf(c4);
      q[2] = f2bf(c5);
      q[3] = f2bf(c6);
      q[4] = f2bf(c7);
      q[5] = f2bf(c8);
    }
    bred[t] = bsum;
    __syncthreads();
    if (t < 32) {
      float s = 0.f;
#pragma unroll
      for (int g = 0; g < 8; ++g) s += bred[g * 32 + t];
      partB[(size_t)(b & 31) * O_DIM + o0 + t] = s;
    }
    const u32x4* lsrc = (const u32x4*)tile;
#pragma unroll
    for (int r = 0; r < 3; ++r) {
      int c = t + r * 256;
      int row = c / 24, off = c % 24;
      u32x4* gdst = (u32x4*)(Bt + (size_t)(o0 + row) * K_DIM + (size_t)i0 * 6 + off * 8);
      *gdst = lsrc[c];
    }
  }
}

// ---------------- Kernel 2b: final bias reduce (32 partials) -----------------
__global__ __launch_bounds__(256) void k_bias2(const float* __restrict__ partB,
                                               float* __restrict__ bias) {
  int o = blockIdx.x * 256 + threadIdx.x;     // 4 blocks
  float s = 0.f;
#pragma unroll
  for (int ib = 0; ib < 32; ++ib) s += partB[(size_t)ib * O_DIM + o];
  bias[o] = s;
}

// ---------------- Kernel 3: 256x256 bf16 GEMM, BK=32, 2 blocks/CU ------------
// 512 thr = 8 waves (2M x 4N); per-wave C = 128x64. LDS dbuf 64KB -> 2 blk/CU.
// Unroll-2 read-ahead: stage(nb,t+1) -> 32 MFMA(cur frags, pre-read) ->
// vmcnt(0)+barrier -> stage(cur,t+2) + readK(nb) -> ... 1 barrier per tile.
// TLP across the two co-resident blocks hides drains and read latency.
// Swizzle for 64B rows: chunk ^= (row>>1)&3 on BOTH source and read side.
#define SBAR __builtin_amdgcn_sched_barrier(0)

template<int NSPLIT>
__global__ __launch_bounds__(512, 2) void k_gemm8(const unsigned short* __restrict__ A,
                                                  const unsigned short* __restrict__ B,
                                                  const float* __restrict__ bias,
                                                  _Float16* __restrict__ part,
                                                  float* __restrict__ out) {
  constexpr int CK = K_DIM / NSPLIT;     // 768 / 1536 / 6144
  constexpr int NT = CK / 32;            // 24 / 48 / 192 (even)
  constexpr int PPX = 2 * NSPLIT;        // (ym,zk) panels per XCD
  __shared__ char lds[65536];            // [2 buf][A 16KB | B 16KB]
  const int tid = threadIdx.x;
  const int lane = tid & 63, wid = tid >> 6;
  const int wm = wid >> 2, wn = wid & 3;
  const int l15 = lane & 15, lk = lane >> 4;
  // XCD-grouped bijective remap: 4 n-blocks of one (ym,zk) panel -> same XCD
  const int flat = blockIdx.x + (blockIdx.y << 2) + (blockIdx.z << 6);
  const int xcd = flat & 7, slot = flat >> 3;
  const int panel = xcd * PPX + (slot >> 2);
  const int xn = slot & 3;
  const int ym = panel & 15, zk = panel >> 4;
  const int m0 = ym * 256, n0 = xn * 256;
  const size_t kb = (size_t)zk * CK;
  // staging: thread covers LDS row tid>>2 (+128), 16B slot tid&3 (linear dest);
  // pre-swizzled global chunk = slot ^ ((row>>1)&3) = (tid&3) ^ ((tid>>3)&3)
  const int srow = tid >> 2;
  const int cg8 = (((tid & 3) ^ ((tid >> 3) & 3)) * 8);    // ushort offset
  // ds_read swizzled chunk: lane chunk lk, row bits from l15
  const int cx = (lk ^ ((l15 >> 1) & 3)) * 16;             // byte offset in 64B row
  const int arow = wm * 128 + l15;
  const int brow = wn * 64 + l15;

  auto gload = [&](const unsigned short* s, int ldsoff) {
    __builtin_amdgcn_global_load_lds((const __attribute__((address_space(1))) void*)s,
        (__attribute__((address_space(3))) void*)(lds + ldsoff), 16, 0, 0);
  };
  auto stageAB = [&](int buf, int kt2) {
    const unsigned short* sa = A + (size_t)(m0 + srow) * K_DIM + kb + (size_t)kt2 * 32 + cg8;
    const unsigned short* sb = B + (size_t)(n0 + srow) * K_DIM + kb + (size_t)kt2 * 32 + cg8;
    int d = buf * 32768 + tid * 16;
    gload(sa, d);
    gload(sa + (size_t)128 * K_DIM, d + 8192);
    gload(sb, d + 16384);
    gload(sb + (size_t)128 * K_DIM, d + 24576);
  };

  short8 aA[8], bA[4], aB[8], bB[4];     // two static frag sets (rule #20)
  f32x4 acc[8][4];
#pragma unroll
  for (int i = 0; i < 8; ++i)
#pragma unroll
    for (int n = 0; n < 4; ++n)
#pragma unroll
      for (int j = 0; j < 4; ++j) acc[i][n][j] = 0.f;

  auto readK = [&](int buf, short8 (&av)[8], short8 (&bv)[4]) {
#pragma unroll
    for (int mi = 0; mi < 8; ++mi)
      av[mi] = *(const short8*)(lds + buf * 32768 + (arow + mi * 16) * 64 + cx);
#pragma unroll
    for (int ni = 0; ni < 4; ++ni)
      bv[ni] = *(const short8*)(lds + buf * 32768 + 16384 + (brow + ni * 16) * 64 + cx);
  };
  auto quadK = [&](short8 (&av)[8], short8 (&bv)[4]) {
#pragma unroll
    for (int mi = 0; mi < 8; ++mi)
#pragma unroll
      for (int ni = 0; ni < 4; ++ni)
        acc[mi][ni] = __builtin_amdgcn_mfma_f32_16x16x32_bf16(av[mi], bv[ni], acc[mi][ni], 0, 0, 0);
  };

  // prologue: stage tile0 -> buf0, drain, barrier, pre-read tile0 frags
  stageAB(0, 0);
  asm volatile("s_waitcnt vmcnt(0)" ::: "memory"); SBAR;
  __builtin_amdgcn_s_barrier(); SBAR;
  readK(0, aA, bA);

#pragma unroll 1
  for (int kt = 0; kt < NT; kt += 2) {
    // tile kt (buf0, frags A): stage kt+1 -> buf1 early, MFMA covers it
    stageAB(1, kt + 1);
    __builtin_amdgcn_s_setprio(1);
    quadK(aA, bA);
    __builtin_amdgcn_s_setprio(0); SBAR;
    asm volatile("s_waitcnt vmcnt(0)" ::: "memory"); SBAR;   // buf1 staged
    __builtin_amdgcn_s_barrier(); SBAR;                      // buf0 free
    // tile kt+1 (buf1, frags B): stage kt+2 -> buf0, read buf1
    if (kt + 2 < NT) stageAB(0, kt + 2);
    readK(1, aB, bB);
    __builtin_amdgcn_s_setprio(1);
    quadK(aB, bB);
    __builtin_amdgcn_s_setprio(0); SBAR;
    if (kt + 2 < NT) {
      asm volatile("s_waitcnt vmcnt(0)" ::: "memory"); SBAR; // buf0 staged
      __builtin_amdgcn_s_barrier(); SBAR;                    // buf1 free
      readK(0, aA, bA);
    }
  }

  // epilogue: C/D layout col = lane&15, row = (lane>>4)*4 + j
  if (NSPLIT > 1) {
    _Float16* base = part + (size_t)zk * ((size_t)M_DIM * O_DIM);
#pragma unroll
    for (int mi = 0; mi < 8; ++mi) {
      int r0 = m0 + wm * 128 + mi * 16 + (lk << 2);
#pragma unroll
      for (int ni = 0; ni < 4; ++ni) {
        int col = n0 + wn * 64 + ni * 16 + l15;
#pragma unroll
        for (int j = 0; j < 4; ++j)
          base[(size_t)(r0 + j) * O_DIM + col] = (_Float16)acc[mi][ni][j];
      }
    }
  } else {
#pragma unroll
    for (int mi = 0; mi < 8; ++mi) {
      int r0 = m0 + wm * 128 + mi * 16 + (lk << 2);
#pragma unroll
      for (int ni = 0; ni < 4; ++ni) {
        int col = n0 + wn * 64 + ni * 16 + l15;
        float bv = bias[col];
#pragma unroll
        for (int j = 0; j < 4; ++j)
          out[(size_t)(r0 + j) * O_DIM + col] = acc[mi][ni][j] + bv;
      }
    }
  }
}

// ---------------- Kernel 4: reduce f16 split-K partials + bias ---------------
template<int NSPLIT>
__global__ __launch_bounds__(256) void k_reduce(const _Float16* __restrict__ part,
                                                const float* __restrict__ bias,
                                                float* __restrict__ out) {
  size_t t = (size_t)blockIdx.x * 256 + threadIdx.x;   // 2048 blocks, 8 out/thread
  size_t idx = t * 8;
  const size_t P = (size_t)M_DIM * O_DIM;
  float r[8];
  size_t bo = idx & (O_DIM - 1);
  f32x4 b0 = *(const f32x4*)(bias + bo);
  f32x4 b1 = *(const f32x4*)(bias + bo + 4);
#pragma unroll
  for (int j = 0; j < 4; ++j) { r[j] = b0[j]; r[j + 4] = b1[j]; }
#pragma unroll
  for (int p = 0; p < NSPLIT; ++p) {
    h16x8 s = *(const h16x8*)(part + (size_t)p * P + idx);
#pragma unroll
    for (int j = 0; j < 8; ++j) r[j] += (float)s[j];
  }
  f32x4 r0, r1;
#pragma unroll
  for (int j = 0; j < 4; ++j) { r0[j] = r[j]; r1[j] = r[j + 4]; }
  *(f32x4*)(out + idx) = r0;
  *(f32x4*)(out + idx + 4) = r1;
}

extern "C" void kernel_launch(void* const* d_in, const int* in_sizes, int n_in,
                              void* d_out, int out_size, void* d_ws, size_t ws_size,
                              hipStream_t stream) {
  const float* x      = (const float*)d_in[0];
  const float* coeffs = (const float*)d_in[1];
  float* out = (float*)d_out;
  char* ws = (char*)d_ws;
  const size_t offA     = 0;
  const size_t offB     = 50331648;                // A: 4096*6144*2
  const size_t offBias  = offB + 12582912;         // Bt: 1024*6144*2
  const size_t offPart  = offBias + 4096;          // partials; partB overlaps
  const size_t offPartB = offPart;                 // (partB dead before gemm writes)
  const size_t planeB   = (size_t)M_DIM * O_DIM * 2;
  const size_t need8 = offPart + 8 * planeB;       // 130,027,520
  const size_t need4 = offPart + 4 * planeB;       //  96,472,064

  unsigned short* A  = (unsigned short*)(ws + offA);
  unsigned short* Bt = (unsigned short*)(ws + offB);
  float* bias        = (float*)(ws + offBias);
  float* partB       = (float*)(ws + offPartB);
  _Float16* part     = (_Float16*)(ws + offPart);

  k_prep<<<3072, 256, 0, stream>>>(x, coeffs, A, Bt, partB);
  k_bias2<<<4, 256, 0, stream>>>(partB, bias);

  if (ws_size >= need8) {
    k_gemm8<8><<<dim3(4, 16, 8), 512, 0, stream>>>(A, Bt, bias, part, out);
    k_reduce<8><<<(M_DIM * O_DIM) / (256 * 8), 256, 0, stream>>>(part, bias, out);
  } else if (ws_size >= need4) {
    k_gemm8<4><<<dim3(4, 16, 4), 512, 0, stream>>>(A, Bt, bias, part, out);
    k_reduce<4><<<(M_DIM * O_DIM) / (256 * 8), 256, 0, stream>>>(part, bias, out);
  } else {
    k_gemm8<1><<<dim3(4, 16, 1), 512, 0, stream>>>(A, Bt, bias, part, out);
  }
}

// Round 10
// 94.342 us; speedup vs baseline: 2.0358x; 1.0989x over previous
//
#include <hip/hip_runtime.h>
#include <stdint.h>

#define M_DIM 4096
#define I_DIM 1024
#define O_DIM 1024
#define KB 6
#define K_DIM (I_DIM * KB)   // 6144
#define SPLITS 4

typedef __attribute__((ext_vector_type(8))) short short8;
typedef __attribute__((ext_vector_type(4))) float f32x4;
typedef __attribute__((ext_vector_type(16))) float f32x16;
typedef __attribute__((ext_vector_type(4))) unsigned int u32x4;
typedef __attribute__((ext_vector_type(4))) float hfloat4;
typedef __attribute__((ext_vector_type(8))) _Float16 h16x8;

__device__ __forceinline__ unsigned short f2bf(float f) {
  union { float f; unsigned int u; } v; v.f = f;
  unsigned int u = v.u;
  unsigned int r = (u + 0x7FFFu + ((u >> 16) & 1u)) >> 16;
  return (unsigned short)r;
}

// ---- Kernel 1 (fat): blocks [0,2048): basis planes -> bf16 A[4096][6144]
//                      blocks [2048,3072): coeffs -> bf16 Bt[1024][6144] + bias partials
__global__ __launch_bounds__(256) void k_prep(const float* __restrict__ x,
                                              const float* __restrict__ C,
                                              unsigned short* __restrict__ A,
                                              unsigned short* __restrict__ Bt,
                                              float* __restrict__ partB) {
  const int bid = blockIdx.x;
  if (bid < 2048) {
    int t = bid * 256 + threadIdx.x;
    long e0 = (long)t * 8;
    const hfloat4* xp = (const hfloat4*)(x + e0);
    hfloat4 v0 = xp[0], v1 = xp[1];
    float xv[8];
    xv[0]=v0[0]; xv[1]=v0[1]; xv[2]=v0[2]; xv[3]=v0[3];
    xv[4]=v1[0]; xv[5]=v1[1]; xv[6]=v1[2]; xv[7]=v1[3];
    unsigned short outv[48];
#pragma unroll
    for (int e = 0; e < 8; ++e) {
      float s  = 1.0f / (1.0f + __expf(-xv[e]));
      float b2 = s, b3 = s, b4 = s * s;
      float b5 = fmaf(s, b4, b3 + b2 + 1.0f);
      float b6 = fmaf(s, b5, b4 + b3 + b2 + 1.0f);
      float b7 = fmaf(s, b6, b5 + b4 + b3 + b2);
      float b8 = fmaf(s, b7, b6 + b5 + b4 + b3);
      outv[e*6+0] = f2bf(s);
      outv[e*6+1] = f2bf(b4);
      outv[e*6+2] = f2bf(b5);
      outv[e*6+3] = f2bf(b6);
      outv[e*6+4] = f2bf(b7);
      outv[e*6+5] = f2bf(b8);
    }
    u32x4* dst = (u32x4*)(A + e0 * KB);
    const u32x4* srcv = (const u32x4*)outv;
#pragma unroll
    for (int q = 0; q < 6; ++q) dst[q] = srcv[q];
  } else {
    __shared__ unsigned short tile[32 * 192];
    __shared__ float bred[256];
    int b = bid - 2048;
    int i0 = (b & 31) * 32, o0 = (b >> 5) * 32;
    int t = threadIdx.x;
    int ol = t & 31, ig = t >> 5;
    float bsum = 0.f;
#pragma unroll
    for (int r = 0; r < 4; ++r) {
      int il = ig + r * 8;
      const float* p = C + (size_t)(i0 + il) * (O_DIM * 9) + (size_t)(o0 + ol) * 9;
      float c1 = p[1];
      float c2 = p[2], c3 = p[3], c4 = p[4], c5 = p[5], c6 = p[6], c7 = p[7], c8 = p[8];
      bsum += c1;
      unsigned short* q = &tile[ol * 192 + il * 6];
      q[0] = f2bf(c2 + c3);
      q[1] = f2bf(c4);
      q[2] = f2bf(c5);
      q[3] = f2bf(c6);
      q[4] = f2bf(c7);
      q[5] = f2bf(c8);
    }
    bred[t] = bsum;
    __syncthreads();
    if (t < 32) {
      float s = 0.f;
#pragma unroll
      for (int g = 0; g < 8; ++g) s += bred[g * 32 + t];
      partB[(size_t)(b & 31) * O_DIM + o0 + t] = s;
    }
    const u32x4* lsrc = (const u32x4*)tile;
#pragma unroll
    for (int r = 0; r < 3; ++r) {
      int c = t + r * 256;
      int row = c / 24, off = c % 24;
      u32x4* gdst = (u32x4*)(Bt + (size_t)(o0 + row) * K_DIM + (size_t)i0 * 6 + off * 8);
      *gdst = lsrc[c];
    }
  }
}

// ---------------- Kernel 2b: final bias reduce (32 partials) -----------------
__global__ __launch_bounds__(256) void k_bias2(const float* __restrict__ partB,
                                               float* __restrict__ bias) {
  int o = blockIdx.x * 256 + threadIdx.x;     // 4 blocks
  float s = 0.f;
#pragma unroll
  for (int ib = 0; ib < 32; ++ib) s += partB[(size_t)ib * O_DIM + o];
  bias[o] = s;
}

// ---------------- Kernel 3: 256x256 bf16 GEMM, 32x32x16 MFMA -----------------
// r7 read-ahead pipeline, BK=64, LDS dbuf 128KB, 8 waves (2M x 4N),
// per-wave C = 128x64 = 4x2 tiles of 32x32 (f32x16 acc each).
// Fragments split by k-half (ks 0-1 / 2-3), 12 b128 reads per half.
// Swizzle identical to r7: 16B-chunk c ^= (row&7), row&7 == lane&7.
#define SBAR __builtin_amdgcn_sched_barrier(0)

template<bool SPLIT>
__global__ __launch_bounds__(512, 2) void k_gemm8(const unsigned short* __restrict__ A,
                                                  const unsigned short* __restrict__ B,
                                                  const float* __restrict__ bias,
                                                  _Float16* __restrict__ part,
                                                  float* __restrict__ out) {
  constexpr int CK = SPLIT ? (K_DIM / SPLITS) : K_DIM;   // 1536 / 6144
  constexpr int NT = CK / 64;                            // 24 / 96
  constexpr int PPX = SPLIT ? 8 : 2;                     // (ym,zk) panels per XCD
  __shared__ char lds[131072];   // [2 buf][A 32KB | B 32KB]
  const int tid = threadIdx.x;
  const int lane = tid & 63, wid = tid >> 6;
  const int wm = wid >> 2, wn = wid & 3;
  const int l31 = lane & 31, lh = lane >> 5, l7 = lane & 7;
  // XCD-grouped bijective remap: 4 n-blocks of one (ym,zk) panel -> same XCD
  const int flat = blockIdx.x + (blockIdx.y << 2) + (blockIdx.z << 6);
  const int xcd = flat & 7, slot = flat >> 3;
  const int panel = xcd * PPX + (slot >> 2);
  const int xn = slot & 3;
  const int ym = panel & 15, zk = panel >> 4;
  const int m0 = ym * 256, n0 = xn * 256;
  const size_t kb = (size_t)zk * CK;
  // staging (unchanged from r7): thread tid covers LDS rows tid>>3 (+64),
  // chunk slot tid&7; pre-swizzled global chunk = slot ^ (row&7)
  const int srow = tid >> 3;
  const int cg8 = (((tid & 7) ^ ((tid >> 3) & 7)) * 8);  // ushort offset
  const int arow = wm * 128 + l31;                       // fragment A row
  const int brow = wn * 64 + l31;                        // fragment B row (o)

  auto gload = [&](const unsigned short* s, int ldsoff) {
    __builtin_amdgcn_global_load_lds((const __attribute__((address_space(1))) void*)s,
        (__attribute__((address_space(3))) void*)(lds + ldsoff), 16, 0, 0);
  };
  auto stageA = [&](int buf, int h, int kt2) {
    const unsigned short* s = A + (size_t)(m0 + h * 128 + srow) * K_DIM + kb + (size_t)kt2 * 64 + cg8;
    int d = buf * 65536 + h * 16384 + tid * 16;
    gload(s, d);
    gload(s + (size_t)64 * K_DIM, d + 8192);
  };
  auto stageB = [&](int buf, int h, int kt2) {
    const unsigned short* s = B + (size_t)(n0 + h * 128 + srow) * K_DIM + kb + (size_t)kt2 * 64 + cg8;
    int d = buf * 65536 + 32768 + h * 16384 + tid * 16;
    gload(s, d);
    gload(s + (size_t)64 * K_DIM, d + 8192);
  };

  // fragments per k-half: A 4 subtiles x 2 ks, B 2 subtiles x 2 ks
  short8 a0[4][2], b0v[2][2], a1[4][2], b1v[2][2];
  f32x16 acc[4][2];
#pragma unroll
  for (int mi = 0; mi < 4; ++mi)
#pragma unroll
    for (int ni = 0; ni < 2; ++ni)
#pragma unroll
      for (int j = 0; j < 16; ++j) acc[mi][ni][j] = 0.f;

  // ds_read: row = base + l31 (row&7 == l7); chunk = ks*2 + lh, swizzled ^l7
  auto readK = [&](int buf, int half, short8 (&av)[4][2], short8 (&bv)[2][2]) {
#pragma unroll
    for (int mi = 0; mi < 4; ++mi)
#pragma unroll
      for (int k2 = 0; k2 < 2; ++k2) {
        int ks = half * 2 + k2;
        int cx = (((ks * 2 + lh) ^ l7) * 16);
        av[mi][k2] = *(const short8*)(lds + buf * 65536 + (arow + mi * 32) * 128 + cx);
      }
#pragma unroll
    for (int ni = 0; ni < 2; ++ni)
#pragma unroll
      for (int k2 = 0; k2 < 2; ++k2) {
        int ks = half * 2 + k2;
        int cx = (((ks * 2 + lh) ^ l7) * 16);
        bv[ni][k2] = *(const short8*)(lds + buf * 65536 + 32768 + (brow + ni * 32) * 128 + cx);
      }
  };
  auto quadK = [&](short8 (&av)[4][2], short8 (&bv)[2][2]) {
#pragma unroll
    for (int mi = 0; mi < 4; ++mi)
#pragma unroll
      for (int ni = 0; ni < 2; ++ni)
#pragma unroll
        for (int k2 = 0; k2 < 2; ++k2)
          acc[mi][ni] = __builtin_amdgcn_mfma_f32_32x32x16_bf16(av[mi][k2], bv[ni][k2],
                                                                acc[mi][ni], 0, 0, 0);
  };

  // prologue: stage tile0 into buf0, drain, barrier, read k-half0 frags
  stageA(0, 0, 0); stageA(0, 1, 0); stageB(0, 0, 0); stageB(0, 1, 0);
  asm volatile("s_waitcnt vmcnt(0)" ::: "memory"); SBAR;
  __builtin_amdgcn_s_barrier(); SBAR;
  readK(0, 0, a0, b0v);

#pragma unroll 1
  for (int kt = 0; kt < NT; ++kt) {
    const int buf = kt & 1, nb = buf ^ 1;
    if (kt + 1 < NT) {
      stageA(nb, 0, kt + 1); stageA(nb, 1, kt + 1);
      stageB(nb, 0, kt + 1); stageB(nb, 1, kt + 1);
    }
    readK(buf, 1, a1, b1v);
    __builtin_amdgcn_s_setprio(1);
    quadK(a0, b0v);          // half0 pre-read: no wait at entry
    quadK(a1, b1v);          // counted lgkmcnt covers half1
    __builtin_amdgcn_s_setprio(0); SBAR;
    asm volatile("s_waitcnt lgkmcnt(0)" ::: "memory"); SBAR;   // WAR: reads done
    if (kt + 1 < NT) {
      asm volatile("s_waitcnt vmcnt(0)" ::: "memory"); SBAR;   // RAW: staging done
      __builtin_amdgcn_s_barrier(); SBAR;
      readK(nb, 0, a0, b0v);   // next tile half0, overlaps next issue+quad
    }
  }

  // epilogue: 32x32 C/D layout: col = lane&31, row = (j&3) + 8*(j>>2) + 4*lh
  if (SPLIT) {
    _Float16* base = part + (size_t)zk * ((size_t)M_DIM * O_DIM);
#pragma unroll
    for (int mi = 0; mi < 4; ++mi) {
      int rb = m0 + wm * 128 + mi * 32 + 4 * lh;
#pragma unroll
      for (int ni = 0; ni < 2; ++ni) {
        int col = n0 + wn * 64 + ni * 32 + l31;
#pragma unroll
        for (int j = 0; j < 16; ++j) {
          int row = rb + (j & 3) + 8 * (j >> 2);
          base[(size_t)row * O_DIM + col] = (_Float16)acc[mi][ni][j];
        }
      }
    }
  } else {
#pragma unroll
    for (int mi = 0; mi < 4; ++mi) {
      int rb = m0 + wm * 128 + mi * 32 + 4 * lh;
#pragma unroll
      for (int ni = 0; ni < 2; ++ni) {
        int col = n0 + wn * 64 + ni * 32 + l31;
        float bv = bias[col];
#pragma unroll
        for (int j = 0; j < 16; ++j) {
          int row = rb + (j & 3) + 8 * (j >> 2);
          out[(size_t)row * O_DIM + col] = acc[mi][ni][j] + bv;
        }
      }
    }
  }
}

// ---------------- Kernel 4: reduce f16 split-K partials + bias ---------------
__global__ __launch_bounds__(256) void k_reduce(const _Float16* __restrict__ part,
                                                const float* __restrict__ bias,
                                                float* __restrict__ out) {
  size_t t = (size_t)blockIdx.x * 256 + threadIdx.x;   // 2048 blocks, 8 out/thread
  size_t idx = t * 8;
  const size_t P = (size_t)M_DIM * O_DIM;
  h16x8 s0 = *(const h16x8*)(part + idx);
  h16x8 s1 = *(const h16x8*)(part + P + idx);
  h16x8 s2 = *(const h16x8*)(part + 2 * P + idx);
  h16x8 s3 = *(const h16x8*)(part + 3 * P + idx);
  size_t bo = idx & (O_DIM - 1);
  f32x4 b0 = *(const f32x4*)(bias + bo);
  f32x4 b1 = *(const f32x4*)(bias + bo + 4);
  f32x4 r0, r1;
#pragma unroll
  for (int j = 0; j < 4; ++j) {
    r0[j] = (((float)s0[j] + (float)s1[j]) + ((float)s2[j] + (float)s3[j])) + b0[j];
    r1[j] = (((float)s0[j+4] + (float)s1[j+4]) + ((float)s2[j+4] + (float)s3[j+4])) + b1[j];
  }
  *(f32x4*)(out + idx) = r0;
  *(f32x4*)(out + idx + 4) = r1;
}

extern "C" void kernel_launch(void* const* d_in, const int* in_sizes, int n_in,
                              void* d_out, int out_size, void* d_ws, size_t ws_size,
                              hipStream_t stream) {
  const float* x      = (const float*)d_in[0];
  const float* coeffs = (const float*)d_in[1];
  float* out = (float*)d_out;
  char* ws = (char*)d_ws;
  const size_t offA     = 0;
  const size_t offB     = 50331648;                // A: 4096*6144*2
  const size_t offBias  = offB + 12582912;         // Bt: 1024*6144*2
  const size_t offPartB = offBias + 4096;          // bias: 1024*4
  const size_t offPart  = offPartB + 131072;       // partB: 32*1024*4
  const size_t needSplit = offPart + (size_t)SPLITS * M_DIM * O_DIM * 2;  // f16 partials

  unsigned short* A  = (unsigned short*)(ws + offA);
  unsigned short* Bt = (unsigned short*)(ws + offB);
  float* bias        = (float*)(ws + offBias);
  float* partB       = (float*)(ws + offPartB);
  _Float16* part     = (_Float16*)(ws + offPart);

  k_prep<<<3072, 256, 0, stream>>>(x, coeffs, A, Bt, partB);
  k_bias2<<<4, 256, 0, stream>>>(partB, bias);

  if (ws_size >= needSplit) {
    k_gemm8<true><<<dim3(4, 16, SPLITS), 512, 0, stream>>>(A, Bt, bias, part, out);
    k_reduce<<<(M_DIM * O_DIM) / (256 * 8), 256, 0, stream>>>(part, bias, out);
  } else {
    k_gemm8<false><<<dim3(4, 16, 1), 512, 0, stream>>>(A, Bt, bias, part, out);
  }
}